// Round 7
// baseline (923.699 us; speedup 1.0000x reference)
//
#include <hip/hip_runtime.h>

// Problem constants (from reference setup_inputs)
#define NE     800000          // edges
#define NHEADS 4               // heads
#define ND     32              // feature dim per head
#define NN     50000           // nodes
#define NSEG   (NN * NHEADS)   // 200000 segment cells
#define NROWS  (NE * NHEADS)   // 3200000 (edge, head) rows

// Native clang vector type — accepted by __builtin_nontemporal_load
// (HIP_vector_type float4 is a struct and is rejected).
typedef float f32x4 __attribute__((ext_vector_type(4)));

// Monotone float<->uint mapping so unsigned atomicMax == float max.
// Identity element: key 0 (all real floats map to key > 0).
__device__ __forceinline__ unsigned f2u_mono(float x) {
    unsigned u = __float_as_uint(x);
    return (u & 0x80000000u) ? ~u : (u | 0x80000000u);
}
__device__ __forceinline__ float u2f_mono(unsigned k) {
    unsigned u = (k & 0x80000000u) ? (k ^ 0x80000000u) : ~k;
    return __uint_as_float(u);
}

// Pass 1: e[row] = sum_d xi*xj*(al*ar); 8 lanes per row, f32x4 per lane.
// A wave (64 lanes) covers 8 consecutive rows = 1KB contiguous per load instr.
// Also atomicMax the per-(node,head) running max (avg 16 updates/cell).
__global__ void k_dot(const float* __restrict__ xi, const float* __restrict__ xj,
                      const float* __restrict__ a, const int* __restrict__ ei,
                      float* __restrict__ e_out, unsigned* __restrict__ seg_max_key) {
    const int tid  = blockIdx.x * blockDim.x + threadIdx.x;
    const int lane = tid & 7;
    const int d0   = lane * 4;
    const int ngroups = (gridDim.x * blockDim.x) >> 3;
    for (int row = tid >> 3; row < NROWS; row += ngroups) {
        const int h = row & (NHEADS - 1);
        const size_t base = (size_t)row * ND + d0;
        const f32x4 vi = __builtin_nontemporal_load(reinterpret_cast<const f32x4*>(xi + base));
        const f32x4 vj = __builtin_nontemporal_load(reinterpret_cast<const f32x4*>(xj + base));
        const f32x4 al = *reinterpret_cast<const f32x4*>(a + h * 2 * ND + d0);
        const f32x4 ar = *reinterpret_cast<const f32x4*>(a + h * 2 * ND + ND + d0);
        float s = 0.0f;
        s = fmaf(vi.x * vj.x, al.x * ar.x, s);
        s = fmaf(vi.y * vj.y, al.y * ar.y, s);
        s = fmaf(vi.z * vj.z, al.z * ar.z, s);
        s = fmaf(vi.w * vj.w, al.w * ar.w, s);
        s += __shfl_xor(s, 1, 8);
        s += __shfl_xor(s, 2, 8);
        s += __shfl_xor(s, 4, 8);
        if (lane == 0) {
            e_out[row] = s;                       // lane0s of a wave hit consecutive rows -> coalesced
            const int edge = row >> 2;            // NHEADS == 4
            const int n = ei[NE + edge];          // seg = edge_index[1]
            atomicMax(&seg_max_key[n * NHEADS + h], f2u_mono(s));
        }
    }
}

// Pass 2 (per edge): e_exp = exp(e - seg_max) for 4 heads at once; in-place on
// d_out; segment-sum via 4 atomicAdds to 16B-contiguous cells.
__global__ void k_exp(const int* __restrict__ ei, const unsigned* __restrict__ seg_max_key,
                      float* __restrict__ e_inout, float* __restrict__ seg_sum) {
    const int edge = blockIdx.x * blockDim.x + threadIdx.x;
    if (edge < NE) {
        const int n = ei[NE + edge];
        const uint4  mk = *reinterpret_cast<const uint4*>(&seg_max_key[n * NHEADS]);
        float4 ev = *reinterpret_cast<float4*>(&e_inout[(size_t)edge * NHEADS]);
        ev.x = expf(ev.x - u2f_mono(mk.x));
        ev.y = expf(ev.y - u2f_mono(mk.y));
        ev.z = expf(ev.z - u2f_mono(mk.z));
        ev.w = expf(ev.w - u2f_mono(mk.w));
        *reinterpret_cast<float4*>(&e_inout[(size_t)edge * NHEADS]) = ev;
        float* cell = &seg_sum[n * NHEADS];
        atomicAdd(cell + 0, ev.x);
        atomicAdd(cell + 1, ev.y);
        atomicAdd(cell + 2, ev.z);
        atomicAdd(cell + 3, ev.w);
    }
}

// Pass 3 (per edge): alpha = e_exp / (seg_sum + 1e-16), vectorized over heads.
__global__ void k_norm(const int* __restrict__ ei, const float* __restrict__ seg_sum,
                       float* __restrict__ e_inout) {
    const int edge = blockIdx.x * blockDim.x + threadIdx.x;
    if (edge < NE) {
        const int n = ei[NE + edge];
        const float4 sv = *reinterpret_cast<const float4*>(&seg_sum[n * NHEADS]);
        float4 ev = *reinterpret_cast<float4*>(&e_inout[(size_t)edge * NHEADS]);
        ev.x = ev.x / (sv.x + 1e-16f);
        ev.y = ev.y / (sv.y + 1e-16f);
        ev.z = ev.z / (sv.z + 1e-16f);
        ev.w = ev.w / (sv.w + 1e-16f);
        *reinterpret_cast<float4*>(&e_inout[(size_t)edge * NHEADS]) = ev;
    }
}

extern "C" void kernel_launch(void* const* d_in, const int* in_sizes, int n_in,
                              void* d_out, int out_size, void* d_ws, size_t ws_size,
                              hipStream_t stream) {
    const float* xi = (const float*)d_in[0];   // x_i  (E,H,D) f32
    const float* xj = (const float*)d_in[1];   // x_j  (E,H,D) f32
    const float* a  = (const float*)d_in[2];   // a    (1,H,2D) f32
    const int*   ei = (const int*)d_in[3];     // edge_index (2,E) int
    float* out = (float*)d_out;                // alpha (E,H,1) f32 — also e / e_exp scratch

    unsigned* seg_max_key = (unsigned*)d_ws;
    float*    seg_sum     = (float*)((char*)d_ws + (size_t)NSEG * sizeof(unsigned));

    // seg_max_key identity (0u) and seg_sum identity (0.0f) are both all-zero bytes.
    (void)hipMemsetAsync(d_ws, 0, (size_t)NSEG * (sizeof(unsigned) + sizeof(float)), stream);

    k_dot <<<2048, 256, 0, stream>>>(xi, xj, a, ei, out, seg_max_key);
    k_exp <<<(NE + 255) / 256, 256, 0, stream>>>(ei, seg_max_key, out, seg_sum);
    k_norm<<<(NE + 255) / 256, 256, 0, stream>>>(ei, seg_sum, out);
}